// Round 2
// baseline (26999.435 us; speedup 1.0000x reference)
//
#include <hip/hip_runtime.h>
#include <math.h>

#define T_SEQ 1024
#define B_SZ  32
#define D_SZ  512
#define H_SZ  256

// ---------------------------------------------------------------------------
// Tiled fp32 GEMMs. BM=BN=64, BK=16, 256 threads, 4x4 per thread.
// ---------------------------------------------------------------------------
#define BM 64
#define BN 64
#define BK 16

// C[M,N] = A[M,K] @ W[N,K]^T (+ bias[n]), batched over blockIdx.z
__global__ __launch_bounds__(256)
void gemm_nt(const float* __restrict__ A, const float* __restrict__ W,
             const float* __restrict__ bias, float* __restrict__ C,
             int M, int N, int K,
             long long sA, long long sW, long long sC)
{
    int z = blockIdx.z;
    A += (size_t)z * sA; W += (size_t)z * sW; C += (size_t)z * sC;
    int n0 = blockIdx.x * BN;
    int m0 = blockIdx.y * BM;
    int tid = threadIdx.x;
    int tm = tid >> 4, tn = tid & 15;

    __shared__ float As[BK][BM + 4];
    __shared__ float Ws[BK][BN + 4];

    float acc[4][4] = {};

    int lc = tid & 15;   // k within tile
    int lr = tid >> 4;   // row base (0..15)

    for (int k0 = 0; k0 < K; k0 += BK) {
        #pragma unroll
        for (int i = 0; i < 4; ++i) {
            int r = lr + 16 * i;
            As[lc][r] = A[(size_t)(m0 + r) * K + k0 + lc];
            Ws[lc][r] = W[(size_t)(n0 + r) * K + k0 + lc];
        }
        __syncthreads();
        #pragma unroll
        for (int kk = 0; kk < BK; ++kk) {
            float4 a4 = *(const float4*)&As[kk][tm * 4];
            float4 b4 = *(const float4*)&Ws[kk][tn * 4];
            float a[4] = {a4.x, a4.y, a4.z, a4.w};
            float b[4] = {b4.x, b4.y, b4.z, b4.w};
            #pragma unroll
            for (int i = 0; i < 4; ++i)
                #pragma unroll
                for (int j = 0; j < 4; ++j)
                    acc[i][j] = fmaf(a[i], b[j], acc[i][j]);
        }
        __syncthreads();
    }

    float bb[4] = {0.f, 0.f, 0.f, 0.f};
    if (bias) {
        #pragma unroll
        for (int j = 0; j < 4; ++j) bb[j] = bias[n0 + tn * 4 + j];
    }
    #pragma unroll
    for (int i = 0; i < 4; ++i) {
        int m = m0 + tm * 4 + i;
        float4 o;
        o.x = acc[i][0] + bb[0];
        o.y = acc[i][1] + bb[1];
        o.z = acc[i][2] + bb[2];
        o.w = acc[i][3] + bb[3];
        *(float4*)&C[(size_t)m * N + n0 + tn * 4] = o;
    }
}

// C[M,N] = A[M,K] @ B[K,N], batched over blockIdx.z
__global__ __launch_bounds__(256)
void gemm_nn(const float* __restrict__ A, const float* __restrict__ B,
             float* __restrict__ C, int M, int N, int K,
             long long sA, long long sB, long long sC)
{
    int z = blockIdx.z;
    A += (size_t)z * sA; B += (size_t)z * sB; C += (size_t)z * sC;
    int n0 = blockIdx.x * BN;
    int m0 = blockIdx.y * BM;
    int tid = threadIdx.x;
    int tm = tid >> 4, tn = tid & 15;

    __shared__ float As[BK][BM + 4];
    __shared__ float Bs[BK][BN + 4];

    float acc[4][4] = {};

    int lc = tid & 15;   // A: k within tile
    int lr = tid >> 4;   // A: row base
    int br = tid >> 6;   // B: k row base (0..3)
    int bc = tid & 63;   // B: col

    for (int k0 = 0; k0 < K; k0 += BK) {
        #pragma unroll
        for (int i = 0; i < 4; ++i) {
            int r = lr + 16 * i;
            As[lc][r] = A[(size_t)(m0 + r) * K + k0 + lc];
        }
        #pragma unroll
        for (int i = 0; i < 4; ++i) {
            int r = br + 4 * i;
            Bs[r][bc] = B[(size_t)(k0 + r) * N + n0 + bc];
        }
        __syncthreads();
        #pragma unroll
        for (int kk = 0; kk < BK; ++kk) {
            float4 a4 = *(const float4*)&As[kk][tm * 4];
            float4 b4 = *(const float4*)&Bs[kk][tn * 4];
            float a[4] = {a4.x, a4.y, a4.z, a4.w};
            float b[4] = {b4.x, b4.y, b4.z, b4.w};
            #pragma unroll
            for (int i = 0; i < 4; ++i)
                #pragma unroll
                for (int j = 0; j < 4; ++j)
                    acc[i][j] = fmaf(a[i], b[j], acc[i][j]);
        }
        __syncthreads();
    }
    #pragma unroll
    for (int i = 0; i < 4; ++i) {
        int m = m0 + tm * 4 + i;
        float4 o;
        o.x = acc[i][0]; o.y = acc[i][1]; o.z = acc[i][2]; o.w = acc[i][3];
        *(float4*)&C[(size_t)m * N + n0 + tn * 4] = o;
    }
}

// ---------------------------------------------------------------------------
// W_hh [4H,H] -> WT [H,4H]  (output-indexed: coalesced writes)
// ---------------------------------------------------------------------------
__global__ __launch_bounds__(256)
void transpose_whh(const float* __restrict__ Wf, const float* __restrict__ Wb,
                   float* __restrict__ WTf, float* __restrict__ WTb)
{
    int idx = blockIdx.x * 256 + threadIdx.x;   // over H*4H = 262144
    int g = idx & (4 * H_SZ - 1);               // 0..1023 (col of WT)
    int k = idx >> 10;                          // 0..255  (row of WT)
    WTf[idx] = Wf[(size_t)g * H_SZ + k];
    WTb[idx] = Wb[(size_t)g * H_SZ + k];
}

// ---------------------------------------------------------------------------
// Single-direction LSTM recurrence. One block per batch element.
// Thread j owns hidden unit j. Gate order: i, f, g, o.
// ---------------------------------------------------------------------------
__global__ __launch_bounds__(256)
void lstm_dir(const float* __restrict__ xg, const float* __restrict__ WT,
              float* __restrict__ xe, int dir)
{
    int b = blockIdx.x;
    int j = threadIdx.x;

    __shared__ float hs[H_SZ];
    hs[j] = 0.f;
    float c = 0.f;
    __syncthreads();

    for (int s = 0; s < T_SEQ; ++s) {
        int t = dir ? (T_SEQ - 1 - s) : s;
        const float* row = xg + ((size_t)b * T_SEQ + t) * (4 * H_SZ);
        float ai = row[j];
        float af = row[H_SZ + j];
        float ag = row[2 * H_SZ + j];
        float ao = row[3 * H_SZ + j];

        #pragma unroll 4
        for (int k = 0; k < H_SZ; ++k) {
            float hk = hs[k];
            const float* w = WT + (size_t)k * (4 * H_SZ);
            ai = fmaf(hk, w[j], ai);
            af = fmaf(hk, w[H_SZ + j], af);
            ag = fmaf(hk, w[2 * H_SZ + j], ag);
            ao = fmaf(hk, w[3 * H_SZ + j], ao);
        }

        float ig = 1.f / (1.f + __expf(-ai));
        float fg = 1.f / (1.f + __expf(-af));
        float gg = tanhf(ag);
        float og = 1.f / (1.f + __expf(-ao));
        c = fg * c + ig * gg;
        float h = og * tanhf(c);

        __syncthreads();          // all reads of old hs done
        hs[j] = h;
        xe[((size_t)b * T_SEQ + t) * D_SZ + dir * H_SZ + j] = h;
        __syncthreads();          // new hs visible for next step
    }
}

// ---------------------------------------------------------------------------
// Masked row softmax over L[b,i,:]. Mask is per query row i: whole row masked
// -> uniform 1/T. One wave per row, 4 rows per block.
//
// Mask dtype probe (bool-uint8 vs int32 storage, both safe):
//   element 1023 of the mask is ALWAYS true (arange(T)>=lengths, lengths<=1023).
//   uint8 storage: byte[1023] == 1. int32 storage: byte[1023] is the high byte
//   of element 255 == 0. Probe reads only byte 1023 (< 32 KiB, safe in both).
// ---------------------------------------------------------------------------
__global__ __launch_bounds__(256)
void softmax_rows(float* __restrict__ L, const void* __restrict__ maskraw)
{
    const unsigned char* mu8 = (const unsigned char*)maskraw;
    const int*           mi32 = (const int*)maskraw;
    bool layout_u8 = (mu8[1023] != 0);

    int lane = threadIdx.x & 63;
    int wid  = threadIdx.x >> 6;
    int row  = (blockIdx.x << 2) + wid;       // 0 .. B*T-1
    float* p = L + (size_t)row * T_SEQ;

    int mval = layout_u8 ? (int)mu8[row] : mi32[row];

    if (mval != 0) {
        const float inv = 1.0f / (float)T_SEQ;
        for (int j = lane; j < T_SEQ; j += 64) p[j] = inv;
        return;
    }

    float v[16];
    float m = -1e30f;
    #pragma unroll
    for (int u = 0; u < 16; ++u) {
        v[u] = p[lane + (u << 6)];
        m = fmaxf(m, v[u]);
    }
    #pragma unroll
    for (int s = 32; s; s >>= 1) m = fmaxf(m, __shfl_xor(m, s, 64));

    float sum = 0.f;
    #pragma unroll
    for (int u = 0; u < 16; ++u) {
        v[u] = __expf(v[u] - m);
        sum += v[u];
    }
    #pragma unroll
    for (int s = 32; s; s >>= 1) sum += __shfl_xor(sum, s, 64);

    float inv = 1.0f / sum;
    #pragma unroll
    for (int u = 0; u < 16; ++u) p[lane + (u << 6)] = v[u] * inv;
}

// ---------------------------------------------------------------------------
// Workspace budget: exactly 192 MiB.
//   ws[0   ..  64 MiB) : xe   [B,T,D] fp32
//   ws[64  .. 192 MiB) : xg   [B,T,4H] fp32 (per direction, reused) -> later L [B,T,T]
// d_out doubles as scratch before the final GEMM:
//   d_out[0..2 MiB)  : WTf, WTb   (dead after LSTM)
//   d_out[0..64 MiB) : proj       (dead after scores GEMM)
// ---------------------------------------------------------------------------
extern "C" void kernel_launch(void* const* d_in, const int* in_sizes, int n_in,
                              void* d_out, int out_size, void* d_ws, size_t ws_size,
                              hipStream_t stream)
{
    const float* x     = (const float*)d_in[0];
    const void*  xmask = d_in[1];
    const float* Wih_f = (const float*)d_in[2];
    const float* Whh_f = (const float*)d_in[3];
    const float* b_f   = (const float*)d_in[4];
    const float* Wih_b = (const float*)d_in[5];
    const float* Whh_b = (const float*)d_in[6];
    const float* b_b   = (const float*)d_in[7];
    const float* W_l   = (const float*)d_in[8];
    float* out = (float*)d_out;

    char* ws = (char*)d_ws;
    const size_t SZ_XE = (size_t)B_SZ * T_SEQ * D_SZ * sizeof(float);     //  64 MiB

    float* xe   = (float*)(ws);
    float* xg   = (float*)(ws + SZ_XE);      // 128 MiB region
    float* L    = xg;                        // reuse after LSTM

    float* WTf  = out;                       // 1 MiB  (d_out scratch)
    float* WTb  = out + 4 * H_SZ * H_SZ;     // 1 MiB
    float* proj = out;                       // 64 MiB (d_out scratch, after WT dead)

    const int MT = B_SZ * T_SEQ;             // 32768
    const long long sTD = (long long)T_SEQ * D_SZ;
    const long long sTT = (long long)T_SEQ * T_SEQ;

    // 1. transpose W_hh for coalesced recurrence access (into d_out scratch)
    transpose_whh<<<dim3((4 * H_SZ * H_SZ) / 256), dim3(256), 0, stream>>>(
        Whh_f, Whh_b, WTf, WTb);

    // 2a. forward input projection xg = x @ W_ih_f^T + b_f
    gemm_nt<<<dim3((4 * H_SZ) / BN, MT / BM, 1), dim3(256), 0, stream>>>(
        x, Wih_f, b_f, xg, MT, 4 * H_SZ, D_SZ, 0, 0, 0);
    // 2b. forward recurrence -> xe[:, :, 0:H]
    lstm_dir<<<dim3(B_SZ), dim3(256), 0, stream>>>(xg, WTf, xe, 0);

    // 3a. backward input projection (same buffer)
    gemm_nt<<<dim3((4 * H_SZ) / BN, MT / BM, 1), dim3(256), 0, stream>>>(
        x, Wih_b, b_b, xg, MT, 4 * H_SZ, D_SZ, 0, 0, 0);
    // 3b. backward recurrence -> xe[:, :, H:2H]
    lstm_dir<<<dim3(B_SZ), dim3(256), 0, stream>>>(xg, WTb, xe, 1);

    // 4. proj = xe @ W_l^T  (into d_out scratch; WT dead)
    gemm_nt<<<dim3(D_SZ / BN, MT / BM, 1), dim3(256), 0, stream>>>(
        xe, W_l, nullptr, proj, MT, D_SZ, D_SZ, 0, 0, 0);

    // 5. scores L[b] = proj[b] @ xe[b]^T  (xg dead -> L)
    gemm_nt<<<dim3(T_SEQ / BN, T_SEQ / BM, B_SZ), dim3(256), 0, stream>>>(
        proj, xe, nullptr, L, T_SEQ, T_SEQ, D_SZ, sTD, sTD, sTT);

    // 6. masked softmax rows (in place)
    softmax_rows<<<dim3(MT / 4), dim3(256), 0, stream>>>(L, xmask);

    // 7. out[b] = A[b] @ xe[b]  (proj dead; final output)
    gemm_nn<<<dim3(D_SZ / BN, T_SEQ / BM, B_SZ), dim3(256), 0, stream>>>(
        L, xe, out, T_SEQ, D_SZ, T_SEQ, sTT, sTD, sTD);
}

// Round 3
// 18516.707 us; speedup vs baseline: 1.4581x; 1.4581x over previous
//
#include <hip/hip_runtime.h>
#include <math.h>

#define T_SEQ 1024
#define B_SZ  32
#define D_SZ  512
#define H_SZ  256

// ---------------------------------------------------------------------------
// Tiled fp32 GEMMs. BM=BN=64, BK=16, 256 threads, 4x4 per thread.
// ---------------------------------------------------------------------------
#define BM 64
#define BN 64
#define BK 16

// C[M,N] = A[M,K] @ W[N,K]^T (+ bias[n]), batched over blockIdx.z
__global__ __launch_bounds__(256)
void gemm_nt(const float* __restrict__ A, const float* __restrict__ W,
             const float* __restrict__ bias, float* __restrict__ C,
             int M, int N, int K,
             long long sA, long long sW, long long sC)
{
    int z = blockIdx.z;
    A += (size_t)z * sA; W += (size_t)z * sW; C += (size_t)z * sC;
    int n0 = blockIdx.x * BN;
    int m0 = blockIdx.y * BM;
    int tid = threadIdx.x;
    int tm = tid >> 4, tn = tid & 15;

    __shared__ float As[BK][BM + 4];
    __shared__ float Ws[BK][BN + 4];

    float acc[4][4] = {};

    int lc = tid & 15;   // k within tile
    int lr = tid >> 4;   // row base (0..15)

    for (int k0 = 0; k0 < K; k0 += BK) {
        #pragma unroll
        for (int i = 0; i < 4; ++i) {
            int r = lr + 16 * i;
            As[lc][r] = A[(size_t)(m0 + r) * K + k0 + lc];
            Ws[lc][r] = W[(size_t)(n0 + r) * K + k0 + lc];
        }
        __syncthreads();
        #pragma unroll
        for (int kk = 0; kk < BK; ++kk) {
            float4 a4 = *(const float4*)&As[kk][tm * 4];
            float4 b4 = *(const float4*)&Ws[kk][tn * 4];
            float a[4] = {a4.x, a4.y, a4.z, a4.w};
            float b[4] = {b4.x, b4.y, b4.z, b4.w};
            #pragma unroll
            for (int i = 0; i < 4; ++i)
                #pragma unroll
                for (int j = 0; j < 4; ++j)
                    acc[i][j] = fmaf(a[i], b[j], acc[i][j]);
        }
        __syncthreads();
    }

    float bb[4] = {0.f, 0.f, 0.f, 0.f};
    if (bias) {
        #pragma unroll
        for (int j = 0; j < 4; ++j) bb[j] = bias[n0 + tn * 4 + j];
    }
    #pragma unroll
    for (int i = 0; i < 4; ++i) {
        int m = m0 + tm * 4 + i;
        float4 o;
        o.x = acc[i][0] + bb[0];
        o.y = acc[i][1] + bb[1];
        o.z = acc[i][2] + bb[2];
        o.w = acc[i][3] + bb[3];
        *(float4*)&C[(size_t)m * N + n0 + tn * 4] = o;
    }
}

// C[M,N] = A[M,K] @ B[K,N], batched over blockIdx.z
__global__ __launch_bounds__(256)
void gemm_nn(const float* __restrict__ A, const float* __restrict__ B,
             float* __restrict__ C, int M, int N, int K,
             long long sA, long long sB, long long sC)
{
    int z = blockIdx.z;
    A += (size_t)z * sA; B += (size_t)z * sB; C += (size_t)z * sC;
    int n0 = blockIdx.x * BN;
    int m0 = blockIdx.y * BM;
    int tid = threadIdx.x;
    int tm = tid >> 4, tn = tid & 15;

    __shared__ float As[BK][BM + 4];
    __shared__ float Bs[BK][BN + 4];

    float acc[4][4] = {};

    int lc = tid & 15;   // A: k within tile
    int lr = tid >> 4;   // A: row base
    int br = tid >> 6;   // B: k row base (0..3)
    int bc = tid & 63;   // B: col

    for (int k0 = 0; k0 < K; k0 += BK) {
        #pragma unroll
        for (int i = 0; i < 4; ++i) {
            int r = lr + 16 * i;
            As[lc][r] = A[(size_t)(m0 + r) * K + k0 + lc];
        }
        #pragma unroll
        for (int i = 0; i < 4; ++i) {
            int r = br + 4 * i;
            Bs[r][bc] = B[(size_t)(k0 + r) * N + n0 + bc];
        }
        __syncthreads();
        #pragma unroll
        for (int kk = 0; kk < BK; ++kk) {
            float4 a4 = *(const float4*)&As[kk][tm * 4];
            float4 b4 = *(const float4*)&Bs[kk][tn * 4];
            float a[4] = {a4.x, a4.y, a4.z, a4.w};
            float b[4] = {b4.x, b4.y, b4.z, b4.w};
            #pragma unroll
            for (int i = 0; i < 4; ++i)
                #pragma unroll
                for (int j = 0; j < 4; ++j)
                    acc[i][j] = fmaf(a[i], b[j], acc[i][j]);
        }
        __syncthreads();
    }
    #pragma unroll
    for (int i = 0; i < 4; ++i) {
        int m = m0 + tm * 4 + i;
        float4 o;
        o.x = acc[i][0]; o.y = acc[i][1]; o.z = acc[i][2]; o.w = acc[i][3];
        *(float4*)&C[(size_t)m * N + n0 + tn * 4] = o;
    }
}

// ---------------------------------------------------------------------------
// Pack W_hh [4H,H] into gate-packed WT4 [H_k][H_u] float4:
//   WT4[k][u] = { W[u][k], W[H+u][k], W[2H+u][k], W[3H+u][k] }
// so the recurrence loads one float4 per (k,u) instead of 4 scalars.
// ---------------------------------------------------------------------------
__global__ __launch_bounds__(256)
void pack_whh(const float* __restrict__ Wf, const float* __restrict__ Wb,
              float4* __restrict__ WT4f, float4* __restrict__ WT4b)
{
    int idx = blockIdx.x * 256 + threadIdx.x;   // over H*H = 65536
    int u = idx & (H_SZ - 1);
    int k = idx >> 8;
    float4 f, g;
    f.x = Wf[((size_t)(0 * H_SZ + u)) * H_SZ + k];
    f.y = Wf[((size_t)(1 * H_SZ + u)) * H_SZ + k];
    f.z = Wf[((size_t)(2 * H_SZ + u)) * H_SZ + k];
    f.w = Wf[((size_t)(3 * H_SZ + u)) * H_SZ + k];
    g.x = Wb[((size_t)(0 * H_SZ + u)) * H_SZ + k];
    g.y = Wb[((size_t)(1 * H_SZ + u)) * H_SZ + k];
    g.z = Wb[((size_t)(2 * H_SZ + u)) * H_SZ + k];
    g.w = Wb[((size_t)(3 * H_SZ + u)) * H_SZ + k];
    WT4f[idx] = f;
    WT4b[idx] = g;
}

// ---------------------------------------------------------------------------
// Single-direction LSTM recurrence, wide version.
// One block of 1024 threads per batch element: 4 k-slices x 256 units.
// Thread (slice, u) computes the partial gate sums for unit u over
// k in [slice*64, slice*64+64), via gate-packed float4 weight loads.
// Owners (slice 0) reduce partials from LDS, apply activations, update c,h.
// ---------------------------------------------------------------------------
__global__ __launch_bounds__(1024)
void lstm_dir4(const float* __restrict__ xg, const float4* __restrict__ WT4,
               float* __restrict__ xe, int dir)
{
    int b     = blockIdx.x;
    int tid   = threadIdx.x;
    int u     = tid & (H_SZ - 1);
    int slice = tid >> 8;          // 0..3
    int k0    = slice << 6;        // 0,64,128,192

    __shared__ float  hs[H_SZ];          // 1 KB
    __shared__ float4 part[4][H_SZ];     // 16 KB

    if (tid < H_SZ) hs[tid] = 0.f;
    float c = 0.f;
    __syncthreads();

    const float4* wbase = WT4 + (size_t)k0 * H_SZ + u;

    for (int s = 0; s < T_SEQ; ++s) {
        int t = dir ? (T_SEQ - 1 - s) : s;

        // owners prefetch xg row into registers (hidden under FMA loop)
        float xi = 0.f, xf = 0.f, xgv = 0.f, xo = 0.f;
        if (tid < H_SZ) {
            const float* row = xg + ((size_t)b * T_SEQ + t) * (4 * H_SZ);
            xi  = row[u];
            xf  = row[H_SZ + u];
            xgv = row[2 * H_SZ + u];
            xo  = row[3 * H_SZ + u];
        }

        float4 acc; acc.x = 0.f; acc.y = 0.f; acc.z = 0.f; acc.w = 0.f;
        #pragma unroll 4
        for (int q = 0; q < 16; ++q) {
            float4 hv = *(const float4*)&hs[k0 + (q << 2)];
            float4 w0 = wbase[(q * 4 + 0) * H_SZ];
            float4 w1 = wbase[(q * 4 + 1) * H_SZ];
            float4 w2 = wbase[(q * 4 + 2) * H_SZ];
            float4 w3 = wbase[(q * 4 + 3) * H_SZ];
            acc.x = fmaf(hv.x, w0.x, acc.x);
            acc.y = fmaf(hv.x, w0.y, acc.y);
            acc.z = fmaf(hv.x, w0.z, acc.z);
            acc.w = fmaf(hv.x, w0.w, acc.w);
            acc.x = fmaf(hv.y, w1.x, acc.x);
            acc.y = fmaf(hv.y, w1.y, acc.y);
            acc.z = fmaf(hv.y, w1.z, acc.z);
            acc.w = fmaf(hv.y, w1.w, acc.w);
            acc.x = fmaf(hv.z, w2.x, acc.x);
            acc.y = fmaf(hv.z, w2.y, acc.y);
            acc.z = fmaf(hv.z, w2.z, acc.z);
            acc.w = fmaf(hv.z, w2.w, acc.w);
            acc.x = fmaf(hv.w, w3.x, acc.x);
            acc.y = fmaf(hv.w, w3.y, acc.y);
            acc.z = fmaf(hv.w, w3.z, acc.z);
            acc.w = fmaf(hv.w, w3.w, acc.w);
        }
        part[slice][u] = acc;
        __syncthreads();   // all partials visible; all hs reads of step s done

        if (tid < H_SZ) {
            float4 p0 = part[0][u], p1 = part[1][u], p2 = part[2][u], p3 = part[3][u];
            float ai = xi  + p0.x + p1.x + p2.x + p3.x;
            float af = xf  + p0.y + p1.y + p2.y + p3.y;
            float ag = xgv + p0.z + p1.z + p2.z + p3.z;
            float ao = xo  + p0.w + p1.w + p2.w + p3.w;
            float ig = 1.f / (1.f + __expf(-ai));
            float fg = 1.f / (1.f + __expf(-af));
            float gg = tanhf(ag);
            float og = 1.f / (1.f + __expf(-ao));
            c = fg * c + ig * gg;
            float h = og * tanhf(c);
            hs[u] = h;
            xe[((size_t)b * T_SEQ + t) * D_SZ + dir * H_SZ + u] = h;
        }
        __syncthreads();   // new hs visible before next step's FMA loop
    }
}

// ---------------------------------------------------------------------------
// Masked row softmax over L[b,i,:]. Mask is per query row i: whole row masked
// -> uniform 1/T. One wave per row, 4 rows per block.
//
// Mask dtype probe (bool-uint8 vs int32 storage, both safe):
//   element 1023 of the mask is ALWAYS true (arange(T)>=lengths, lengths<=1023).
//   uint8 storage: byte[1023] == 1. int32 storage: byte[1023] is the high byte
//   of element 255 == 0. Probe reads only byte 1023 (< 32 KiB, safe in both).
// ---------------------------------------------------------------------------
__global__ __launch_bounds__(256)
void softmax_rows(float* __restrict__ L, const void* __restrict__ maskraw)
{
    const unsigned char* mu8 = (const unsigned char*)maskraw;
    const int*           mi32 = (const int*)maskraw;
    bool layout_u8 = (mu8[1023] != 0);

    int lane = threadIdx.x & 63;
    int wid  = threadIdx.x >> 6;
    int row  = (blockIdx.x << 2) + wid;       // 0 .. B*T-1
    float* p = L + (size_t)row * T_SEQ;

    int mval = layout_u8 ? (int)mu8[row] : mi32[row];

    if (mval != 0) {
        const float inv = 1.0f / (float)T_SEQ;
        for (int j = lane; j < T_SEQ; j += 64) p[j] = inv;
        return;
    }

    float v[16];
    float m = -1e30f;
    #pragma unroll
    for (int u = 0; u < 16; ++u) {
        v[u] = p[lane + (u << 6)];
        m = fmaxf(m, v[u]);
    }
    #pragma unroll
    for (int s = 32; s; s >>= 1) m = fmaxf(m, __shfl_xor(m, s, 64));

    float sum = 0.f;
    #pragma unroll
    for (int u = 0; u < 16; ++u) {
        v[u] = __expf(v[u] - m);
        sum += v[u];
    }
    #pragma unroll
    for (int s = 32; s; s >>= 1) sum += __shfl_xor(sum, s, 64);

    float inv = 1.0f / sum;
    #pragma unroll
    for (int u = 0; u < 16; ++u) p[lane + (u << 6)] = v[u] * inv;
}

// ---------------------------------------------------------------------------
// Workspace budget: exactly 192 MiB.
//   ws[0   ..  64 MiB) : xe   [B,T,D] fp32
//   ws[64  .. 192 MiB) : xg   [B,T,4H] fp32 (per direction, reused) -> later L [B,T,T]
// d_out doubles as scratch before the final GEMM:
//   d_out[0..2 MiB)  : WT4f, WT4b  (dead after LSTM)
//   d_out[0..64 MiB) : proj        (dead after scores GEMM)
// ---------------------------------------------------------------------------
extern "C" void kernel_launch(void* const* d_in, const int* in_sizes, int n_in,
                              void* d_out, int out_size, void* d_ws, size_t ws_size,
                              hipStream_t stream)
{
    const float* x     = (const float*)d_in[0];
    const void*  xmask = d_in[1];
    const float* Wih_f = (const float*)d_in[2];
    const float* Whh_f = (const float*)d_in[3];
    const float* b_f   = (const float*)d_in[4];
    const float* Wih_b = (const float*)d_in[5];
    const float* Whh_b = (const float*)d_in[6];
    const float* b_b   = (const float*)d_in[7];
    const float* W_l   = (const float*)d_in[8];
    float* out = (float*)d_out;

    char* ws = (char*)d_ws;
    const size_t SZ_XE = (size_t)B_SZ * T_SEQ * D_SZ * sizeof(float);     //  64 MiB

    float* xe   = (float*)(ws);
    float* xg   = (float*)(ws + SZ_XE);      // 128 MiB region
    float* L    = xg;                        // reuse after LSTM

    float4* WT4f = (float4*)out;             // 1 MiB  (d_out scratch)
    float4* WT4b = (float4*)out + H_SZ * H_SZ;
    float*  proj = out;                      // 64 MiB (d_out scratch, after WT dead)

    const int MT = B_SZ * T_SEQ;             // 32768
    const long long sTD = (long long)T_SEQ * D_SZ;
    const long long sTT = (long long)T_SEQ * T_SEQ;

    // 1. gate-pack W_hh for the recurrence (into d_out scratch)
    pack_whh<<<dim3((H_SZ * H_SZ) / 256), dim3(256), 0, stream>>>(
        Whh_f, Whh_b, WT4f, WT4b);

    // 2a. forward input projection xg = x @ W_ih_f^T + b_f
    gemm_nt<<<dim3((4 * H_SZ) / BN, MT / BM, 1), dim3(256), 0, stream>>>(
        x, Wih_f, b_f, xg, MT, 4 * H_SZ, D_SZ, 0, 0, 0);
    // 2b. forward recurrence -> xe[:, :, 0:H]
    lstm_dir4<<<dim3(B_SZ), dim3(1024), 0, stream>>>(xg, WT4f, xe, 0);

    // 3a. backward input projection (same buffer)
    gemm_nt<<<dim3((4 * H_SZ) / BN, MT / BM, 1), dim3(256), 0, stream>>>(
        x, Wih_b, b_b, xg, MT, 4 * H_SZ, D_SZ, 0, 0, 0);
    // 3b. backward recurrence -> xe[:, :, H:2H]
    lstm_dir4<<<dim3(B_SZ), dim3(1024), 0, stream>>>(xg, WT4b, xe, 1);

    // 4. proj = xe @ W_l^T  (into d_out scratch; WT dead)
    gemm_nt<<<dim3(D_SZ / BN, MT / BM, 1), dim3(256), 0, stream>>>(
        xe, W_l, nullptr, proj, MT, D_SZ, D_SZ, 0, 0, 0);

    // 5. scores L[b] = proj[b] @ xe[b]^T  (xg dead -> L)
    gemm_nt<<<dim3(T_SEQ / BN, T_SEQ / BM, B_SZ), dim3(256), 0, stream>>>(
        proj, xe, nullptr, L, T_SEQ, T_SEQ, D_SZ, sTD, sTD, sTT);

    // 6. masked softmax rows (in place)
    softmax_rows<<<dim3(MT / 4), dim3(256), 0, stream>>>(L, xmask);

    // 7. out[b] = A[b] @ xe[b]  (proj dead; final output)
    gemm_nn<<<dim3(D_SZ / BN, T_SEQ / BM, B_SZ), dim3(256), 0, stream>>>(
        L, xe, out, T_SEQ, D_SZ, T_SEQ, sTT, sTD, sTD);
}